// Round 15
// baseline (227.117 us; speedup 1.0000x reference)
//
#include <hip/hip_runtime.h>

#define KE_CONST 14.3996454784255f

#define CHUNK_N  33344            // nodes per scan chunk (133,376 B LDS acc; <=160 KB cap)
#define SCAN_THR 1024
#define MAXC     4
#define MAXE     16               // pair table up to 256 entries (4 KB LDS)
#define ELEM_CAP 131072           // 128 KB LDS elem table cap (dense); also r fits 17 bits
#define DN_THR   1024
#define DN_BLOCKS 256

// ---------------- prep A: per-node element id (argmax over attrs) ----------------
__global__ void zbl_prep_elem(const float* __restrict__ node_attrs,
                              unsigned char* __restrict__ elem,
                              int n_nodes, int n_elem) {
    int n = blockIdx.x * blockDim.x + threadIdx.x;
    if (n >= n_nodes) return;
    const float* row = node_attrs + (size_t)n * n_elem;
    float best = row[0];
    int bi = 0;
    for (int i = 1; i < n_elem; ++i) {
        float v = row[i];
        if (v > best) { best = v; bi = i; }
    }
    elem[n] = (unsigned char)bi;
}

// ---------------- prep B: n_elem^2 pair table ----------------
__global__ void zbl_prep_pairs(const int* __restrict__ atomic_numbers,
                               const float* __restrict__ covalent_radii,
                               float4* __restrict__ pair_tab,
                               int n_elem) {
    int t = threadIdx.x;
    int np = n_elem * n_elem;
    if (t >= np) return;
    int eu = t / n_elem;
    int ev = t - eu * n_elem;
    int Zu = atomic_numbers[eu];
    int Zv = atomic_numbers[ev];
    float zu = (float)Zu, zv = (float)Zv;
    float inv_a = (__powf(zu, 0.3f) + __powf(zv, 0.3f)) * (1.0f / (0.4543f * 0.529f));
    float kezz  = 0.5f * KE_CONST * zu * zv;
    float rmax  = covalent_radii[Zu] + covalent_radii[Zv];
    pair_tab[t] = make_float4(inv_a, kezz, rmax, 1.0f / rmax);
}

// ---------------- per-edge e8m7 value from pair-table entry ----------------
__device__ __forceinline__ unsigned enc_val_p(float xv, const float4& p) {
    float t = xv * p.x;
    float phi = 0.1818f  * __expf(-3.2f    * t)
              + 0.5099f  * __expf(-0.9423f * t)
              + 0.2802f  * __expf(-0.4028f * t)
              + 0.02817f * __expf(-0.2016f * t);
    float rr = xv * p.w;
    float r2 = rr * rr;
    float r6 = r2 * r2 * r2;
    float env = 1.0f - 28.0f * r6 + 48.0f * r6 * rr - 21.0f * r6 * r2;
    float val = fmaxf(p.y * phi / xv * env, 0.0f);     // clamp r->1 cancellation negatives
    unsigned e = (__float_as_uint(val) + 0x8000u) >> 16;
    if (e > 0x7FFFu) e = 0x7FFFu;
    return (xv < p.z) ? e : 0u;
}

// ---------------- pass 1: dense streaming compute -> packed u32 per edge ----------------
// (proven: elem table in LDS kills gather latency; ~15-20 us)
__global__ __launch_bounds__(DN_THR)
void zbl_dense_lds(const float* __restrict__ x,
                   const int* __restrict__ ei,
                   const unsigned char* __restrict__ elem_g,
                   const float4* __restrict__ pair_tab,
                   unsigned* __restrict__ packed,
                   int n_edges, int n_elem, int n_nodes) {
    __shared__ __align__(16) unsigned char elem[ELEM_CAP];
    __shared__ float4 pt[MAXE * MAXE];

    int np = n_elem * n_elem;
    for (int i = threadIdx.x; i < np; i += DN_THR) pt[i] = pair_tab[i];
    int nwords = (n_nodes + 15) >> 4;
    const uint4* eg4 = (const uint4*)elem_g;
    uint4* el4 = (uint4*)elem;
    for (int i = threadIdx.x; i < nwords; i += DN_THR) el4[i] = eg4[i];
    __syncthreads();

    long long e0 = (((long long)blockIdx.x * n_edges) / DN_BLOCKS) & ~3LL;
    long long e1 = (blockIdx.x == DN_BLOCKS - 1)
                     ? (long long)n_edges
                     : ((((long long)(blockIdx.x + 1) * n_edges) / DN_BLOCKS) & ~3LL);
    long long vend = e1 & ~3LL;

    for (long long b = e0 + (long long)threadIdx.x * 4; b + 4 <= vend;
         b += (long long)DN_THR * 4) {
        int4   s4 = *(const int4*)(ei + b);
        int4   r4 = *(const int4*)(ei + n_edges + b);
        float4 x4 = *(const float4*)(x + b);
        unsigned es0 = elem[s4.x], es1 = elem[s4.y], es2 = elem[s4.z], es3 = elem[s4.w];
        unsigned er0 = elem[r4.x], er1 = elem[r4.y], er2 = elem[r4.z], er3 = elem[r4.w];
        float4 p0 = pt[es0 * n_elem + er0];
        float4 p1 = pt[es1 * n_elem + er1];
        float4 p2 = pt[es2 * n_elem + er2];
        float4 p3 = pt[es3 * n_elem + er3];
        uint4 o;
        o.x = ((unsigned)r4.x << 15) | enc_val_p(x4.x, p0);
        o.y = ((unsigned)r4.y << 15) | enc_val_p(x4.y, p1);
        o.z = ((unsigned)r4.z << 15) | enc_val_p(x4.z, p2);
        o.w = ((unsigned)r4.w << 15) | enc_val_p(x4.w, p3);
        *(uint4*)(packed + b) = o;
    }
    for (long long e = vend + threadIdx.x; e < e1; e += DN_THR) {
        int r = ei[n_edges + e];
        float4 p = pt[elem[ei[e]] * n_elem + elem[r]];
        packed[e] = ((unsigned)r << 15) | enc_val_p(x[e], p);
    }
}

// ---------------- pass 2: chunked scan — BRANCHLESS inner loop, C=3 range chunks ----------------
// Round-14 finding: predicated atomics compile to exec-mask branch sequences (4 per
// uint4) that serialize the loop; out-of-chunk lanes now add 0.0f to a spread dummy
// slot instead (2 v_cndmask, zero branches). CHUNK_N=33344 -> C=3, 25% less re-scan.
__device__ __forceinline__ void scan_one(unsigned p, int lo, float* acc) {
    unsigned r = p >> 15;
    int li = (int)r - lo;
    bool in = (unsigned)li < (unsigned)CHUNK_N;
    float v = __uint_as_float((p & 0x7FFFu) << 16);
    atomicAdd(&acc[in ? li : (int)(r & 8191u)], in ? v : 0.0f);
}

__global__ __launch_bounds__(SCAN_THR)
void zbl_scan(const unsigned* __restrict__ packed,
              float* __restrict__ partial,
              int n_edges, int B2) {
    int c = blockIdx.x / B2;
    int j = blockIdx.x - c * B2;
    int lo = c * CHUNK_N;

    __shared__ __align__(16) float acc[CHUNK_N];
    for (int i = threadIdx.x * 4; i < CHUNK_N; i += SCAN_THR * 4)
        *(float4*)&acc[i] = make_float4(0.f, 0.f, 0.f, 0.f);
    __syncthreads();

    long long e0 = (((long long)j * n_edges) / B2) & ~3LL;
    long long e1 = (j == B2 - 1) ? (long long)n_edges
                                 : ((((long long)(j + 1) * n_edges) / B2) & ~3LL);
    long long vend = e1 & ~3LL;

    for (long long b = e0 + (long long)threadIdx.x * 4; b + 4 <= vend;
         b += (long long)SCAN_THR * 4) {
        uint4 p = *(const uint4*)(packed + b);
        scan_one(p.x, lo, acc);
        scan_one(p.y, lo, acc);
        scan_one(p.z, lo, acc);
        scan_one(p.w, lo, acc);
    }
    for (long long e = vend + threadIdx.x; e < e1; e += SCAN_THR) {
        unsigned w = packed[e];
        scan_one(w, lo, acc);
    }

    __syncthreads();
    float* pp = partial + (size_t)blockIdx.x * CHUNK_N;
    for (int i = threadIdx.x * 4; i < CHUNK_N; i += SCAN_THR * 4)
        *(float4*)(pp + i) = *(const float4*)&acc[i];
}

// ---------------- pass 3: reduce B2 partials per node, overwrite out ----------------
__global__ void zbl_reduce(const float* __restrict__ partial,
                           float* __restrict__ out,
                           int n_nodes, int B2) {
    int i = blockIdx.x * blockDim.x + threadIdx.x;
    if (i >= n_nodes) return;
    int c  = i / CHUNK_N;            // constant divisor -> magic mul
    int li = i - c * CHUNK_N;
    const float* p = partial + ((size_t)c * B2) * CHUNK_N + li;
    float s0 = 0.f, s1 = 0.f, s2 = 0.f, s3 = 0.f;
    int j = 0;
    for (; j + 4 <= B2; j += 4) {
        s0 += p[(size_t)(j + 0) * CHUNK_N];
        s1 += p[(size_t)(j + 1) * CHUNK_N];
        s2 += p[(size_t)(j + 2) * CHUNK_N];
        s3 += p[(size_t)(j + 3) * CHUNK_N];
    }
    for (; j < B2; ++j) s0 += p[(size_t)j * CHUNK_N];
    out[i] = (s0 + s1) + (s2 + s3);
}

// ================= fallback path: node float4 table + direct device atomics =================
__global__ void zbl_node_prep(const float* __restrict__ node_attrs,
                              const int* __restrict__ atomic_numbers,
                              const float* __restrict__ covalent_radii,
                              float4* __restrict__ node_data,
                              float* __restrict__ out_zero,
                              int n_nodes, int n_elem) {
    int n = blockIdx.x * blockDim.x + threadIdx.x;
    if (n >= n_nodes) return;
    const float* row = node_attrs + (size_t)n * n_elem;
    float best = row[0];
    int bi = 0;
    for (int i = 1; i < n_elem; ++i) {
        float v = row[i];
        if (v > best) { best = v; bi = i; }
    }
    int Z = atomic_numbers[bi];
    float zf = (float)Z;
    node_data[n] = make_float4(zf, __powf(zf, 0.3f), covalent_radii[Z], 0.0f);
    out_zero[n] = 0.0f;
}

__global__ void zbl_edge_atomic(const float* __restrict__ x,
                                const int* __restrict__ edge_index,
                                const float4* __restrict__ node_data,
                                float* __restrict__ out,
                                int n_edges) {
    int e = blockIdx.x * blockDim.x + threadIdx.x;
    if (e >= n_edges) return;
    int snd = edge_index[e];
    int r = edge_index[n_edges + e];
    float xv = x[e];
    float4 du = node_data[snd];
    float4 dv = node_data[r];
    float rmax = du.z + dv.z;
    if (xv >= rmax) return;
    const float inv_a_pref = 1.0f / (0.4543f * 0.529f);
    float t = xv * (du.y + dv.y) * inv_a_pref;
    float phi = 0.1818f  * __expf(-3.2f    * t)
              + 0.5099f  * __expf(-0.9423f * t)
              + 0.2802f  * __expf(-0.4028f * t)
              + 0.02817f * __expf(-0.2016f * t);
    float v = KE_CONST * du.x * dv.x * phi / xv;
    float rr = xv / rmax;
    float r2 = rr * rr;
    float r6 = r2 * r2 * r2;
    float env = 1.0f - 28.0f * r6 + 48.0f * r6 * rr - 21.0f * r6 * r2;
    atomicAdd(&out[r], 0.5f * v * env);
}

extern "C" void kernel_launch(void* const* d_in, const int* in_sizes, int n_in,
                              void* d_out, int out_size, void* d_ws, size_t ws_size,
                              hipStream_t stream) {
    const float* x              = (const float*)d_in[0];
    const float* node_attrs     = (const float*)d_in[1];
    const int*   edge_index     = (const int*)d_in[2];
    const int*   atomic_numbers = (const int*)d_in[3];
    const float* covalent_radii = (const float*)d_in[4];
    float* out = (float*)d_out;

    int n_edges = in_sizes[0];
    int n_elem  = in_sizes[3];
    int n_nodes = in_sizes[1] / n_elem;

    int C  = (n_nodes + CHUNK_N - 1) / CHUNK_N;
    int B2 = 256 / (C < 1 ? 1 : C);
    if (B2 < 1) B2 = 1;
    size_t elem_bytes   = (((size_t)n_nodes) + 255) & ~(size_t)255;
    size_t pair_bytes   = ((size_t)MAXE * MAXE * sizeof(float4) + 255) & ~(size_t)255;
    size_t packed_bytes = (((size_t)n_edges * sizeof(unsigned)) + 255) & ~(size_t)255;
    size_t part_bytes   = (size_t)C * B2 * CHUNK_N * sizeof(float);
    bool fast = (C >= 1) && (C <= MAXC) && (n_nodes <= ELEM_CAP) &&
                (n_elem >= 1) && (n_elem <= MAXE) &&
                (ws_size >= elem_bytes + pair_bytes + packed_bytes + part_bytes);

    if (fast) {
        unsigned char* elem     = (unsigned char*)d_ws;
        float4*        pair_tab = (float4*)((char*)d_ws + elem_bytes);
        unsigned*      packed   = (unsigned*)((char*)d_ws + elem_bytes + pair_bytes);
        float*         part     = (float*)((char*)d_ws + elem_bytes + pair_bytes + packed_bytes);

        zbl_prep_elem<<<(n_nodes + 255) / 256, 256, 0, stream>>>(
            node_attrs, elem, n_nodes, n_elem);
        zbl_prep_pairs<<<1, 256, 0, stream>>>(
            atomic_numbers, covalent_radii, pair_tab, n_elem);

        zbl_dense_lds<<<DN_BLOCKS, DN_THR, 0, stream>>>(
            x, edge_index, elem, pair_tab, packed, n_edges, n_elem, n_nodes);

        zbl_scan<<<C * B2, SCAN_THR, 0, stream>>>(packed, part, n_edges, B2);

        zbl_reduce<<<(n_nodes + 255) / 256, 256, 0, stream>>>(part, out, n_nodes, B2);
        return;
    }

    // fallback: node table + plain device atomics
    float4* node_data = (float4*)d_ws;
    zbl_node_prep<<<(n_nodes + 255) / 256, 256, 0, stream>>>(
        node_attrs, atomic_numbers, covalent_radii, node_data,
        out, n_nodes, n_elem);
    zbl_edge_atomic<<<(n_edges + 255) / 256, 256, 0, stream>>>(
        x, edge_index, node_data, out, n_edges);
}